// Round 10
// baseline (294.983 us; speedup 1.0000x reference)
//
#include <hip/hip_runtime.h>
#include <math.h>

#define EPSF 1.1920929e-07f

typedef __attribute__((ext_vector_type(8))) short short8;
typedef __attribute__((ext_vector_type(4))) float f32x4;

// float -> bf16 (RNE)
static __device__ __forceinline__ unsigned short f2bf(float f) {
    unsigned int u = __float_as_uint(f);
    return (unsigned short)((u + 0x7FFFu + ((u >> 16) & 1u)) >> 16);
}
static __device__ __forceinline__ float bf2f(unsigned short u) {
    return __uint_as_float((unsigned int)u << 16);
}

// ---------------------------------------------------------------------------
// prep: four block-uniform roles.
//  blk <  4096 : x->bf16 (4 rows/block) + fused MoE gate (exact fp32)
//  blk <  4416 : weights->bf16 (wcat q|kv|sr, then pw)
//  blk <  4544 : kv_w transpose -> kv_wT[k][o] f32 (coalesced poolkv reads)
//  else        : CPB table MLP row (4096 rows)
// ---------------------------------------------------------------------------
__global__ __launch_bounds__(256) void prep_kernel(
    const float* __restrict__ x,
    const float* __restrict__ wg,  const float* __restrict__ wg0,
    const float* __restrict__ wg1,
    const float* __restrict__ q_w, const float* __restrict__ kv_w,
    const float* __restrict__ sr_w, const float* __restrict__ pw,
    const float* __restrict__ tbl,
    const float* __restrict__ c1w, const float* __restrict__ c1b,
    const float* __restrict__ c2w, const float* __restrict__ c2b,
    unsigned short* __restrict__ xbf, float* __restrict__ gate,
    unsigned short* __restrict__ wcat, unsigned short* __restrict__ pwbf,
    float* __restrict__ kv_wT, float* __restrict__ cpb)
{
    __shared__ float shpad[512];
    const int blk = blockIdx.x;
    const int t   = threadIdx.x;
    if (blk < 4096) {
        const int j = t & 63;                 // lane within wave; wave = row
        const int row = (blk << 2) + (t >> 6);
        float4 v = *(const float4*)(x + (size_t)row*256 + j*4);
        ushort4 o;
        o.x = f2bf(v.x); o.y = f2bf(v.y); o.z = f2bf(v.z); o.w = f2bf(v.w);
        *(ushort4*)(xbf + (size_t)row*256 + j*4) = o;
        float d[10];
#pragma unroll
        for (int f = 0; f < 10; ++f) {
            const float* wf = (f < 4) ? (wg + f*256) : (f < 6) ? (wg0 + (f-4)*256)
                                                               : (wg1 + (f-6)*256);
            float4 wv = *(const float4*)(wf + j*4);
            float s = v.x*wv.x + v.y*wv.y + v.z*wv.z + v.w*wv.w;
            s += __shfl_xor(s, 32); s += __shfl_xor(s, 16); s += __shfl_xor(s, 8);
            s += __shfl_xor(s, 4);  s += __shfl_xor(s, 2);  s += __shfl_xor(s, 1);
            d[f] = s;
        }
        if (j == 0) {
            float e[4];
            float m = fmaxf(fmaxf(d[0],d[1]), fmaxf(d[2],d[3]));
            float ssum = 0.f;
            for (int i = 0; i < 4; ++i) { e[i] = expf(d[i]-m); ssum += e[i]; }
            for (int i = 0; i < 4; ++i) e[i] /= ssum;
            int i1 = 0;
            for (int i = 1; i < 4; ++i) if (e[i] > e[i1]) i1 = i;
            int i2 = -1;
            for (int i = 0; i < 4; ++i) if (i != i1 && (i2 < 0 || e[i] > e[i2])) i2 = i;
            float rs = fmaxf(e[i1] + e[i2], EPSF);
            float rg[4] = {0.f,0.f,0.f,0.f};
            rg[i1] = e[i1] / rs * 2.f;
            rg[i2] = e[i2] / rs * 2.f;
            float sh[4];
            float m1 = fmaxf(fmaxf(d[6],d[7]), fmaxf(d[8],d[9]));
            float s1 = 0.f;
            for (int i = 0; i < 4; ++i) { sh[i] = expf(d[6+i]-m1); s1 += sh[i]; }
            float mm = fmaxf(d[4], d[5]);
            float e0 = expf(d[4]-mm), e1 = expf(d[5]-mm);
            float w00 = e0/(e0+e1)*2.f, w01 = e1/(e0+e1)*2.f;
            float* gr = gate + ((size_t)row << 3);
            for (int i = 0; i < 4; ++i) gr[i]   = w00 * (sh[i]/s1*4.f);
            for (int i = 0; i < 4; ++i) gr[4+i] = w01 * rg[i];
        }
    } else if (blk < 4416) {
        const int e = ((blk - 4096)*256 + t)*4;
        if (e < 262144) {
            int n = e >> 8, k = e & 255;
            const float* src = (n < 256) ? (q_w + n*256) :
                               (n < 768) ? (kv_w + (n-256)*256) : (sr_w + (n-768)*256);
            float4 v = *(const float4*)(src + k);
            ushort4 o;
            o.x = f2bf(v.x); o.y = f2bf(v.y); o.z = f2bf(v.z); o.w = f2bf(v.w);
            *(ushort4*)(wcat + e) = o;
        } else {
            int e2 = e - 262144;
            float4 v = *(const float4*)(pw + e2);
            ushort4 o;
            o.x = f2bf(v.x); o.y = f2bf(v.y); o.z = f2bf(v.z); o.w = f2bf(v.w);
            *(ushort4*)(pwbf + e2) = o;
        }
    } else if (blk < 4544) {
        const int e = ((blk - 4416)*256 + t)*4;     // over 131072 kv_w elems
        int o = e >> 8, k = e & 255;
        float4 v = *(const float4*)(kv_w + e);
        kv_wT[(k+0)*512 + o] = v.x;
        kv_wT[(k+1)*512 + o] = v.y;
        kv_wT[(k+2)*512 + o] = v.z;
        kv_wT[(k+3)*512 + o] = v.w;
    } else {
        const int r = blk - 4544;
        const float c0 = tbl[(size_t)r*2], c1 = tbl[(size_t)r*2+1];
        for (int i = t; i < 512; i += 256)
            shpad[i] = fmaxf(c0*c1w[i*2] + c1*c1w[i*2+1] + c1b[i], 0.f);
        __syncthreads();
        const int hh = t >> 5, dd = t & 31;
        float s = 0.f;
        for (int i = dd; i < 512; i += 32) s += shpad[i] * c2w[hh*512+i];
        for (int off = 16; off; off >>= 1) s += __shfl_xor(s, off, 32);
        if (dd == 0) cpb[((size_t)r << 3) + hh] = s + c2b[hh];
    }
}

// ---------------------------------------------------------------------------
// Persistent n-loop MFMA GEMM, K=256: grid = M/64 blocks (256 -> 1/CU).
// Each wave keeps its 16-row A-strip in 32 VGPRs; loops over 64-col B-chunks
// (32 KB LDS, register-double-buffered, ONE barrier/chunk; prefetch of chunk
// nc+1 hides under the chunk-nc ds_read+MFMA window). K completes per chunk,
// so the epilogue runs per chunk. FLOP order identical to round-9 gemm.
// mode 0: fused q|k|v|sr producer. mode 1: bias-add f32 GEMM.
// ---------------------------------------------------------------------------
__global__ __launch_bounds__(256) void gemm_nloop(
    const unsigned short* __restrict__ A,   // (M,256) bf16
    const unsigned short* __restrict__ W,   // (nTotal,256) bf16
    const float* __restrict__ B0, const float* __restrict__ B1,
    const float* __restrict__ B2,
    int r1, int r2, int nTotal, int mode,
    float* __restrict__ C, int ldc,
    unsigned short* __restrict__ qkv,
    const float* __restrict__ temp, const float* __restrict__ qe)
{
    __shared__ __attribute__((aligned(16))) unsigned short Bt[2][64*264];
    const int m0 = blockIdx.x << 6;
    const int t  = threadIdx.x;
    const int w  = t >> 6;
    const int col16 = t & 15;
    const int quad  = (t & 63) >> 4;

    // A strip in registers
    short8 afr[8];
    {
        const unsigned short* ap = A + (size_t)(m0 + w*16 + col16)*256 + quad*8;
#pragma unroll
        for (int kk = 0; kk < 8; ++kk)
            afr[kk] = *(const short8*)(ap + kk*32);
    }
    // per-row sls (mode 0)
    float sls_r[4];
    if (mode == 0) {
#pragma unroll
        for (int reg = 0; reg < 4; ++reg) {
            int row = (m0 + w*16 + quad*4 + reg) & 4095;
            int y = row >> 6, x = row & 63;
            int cy = (y == 0 || y == 63) ? 2 : 3;
            int cx = (x == 0 || x == 63) ? 2 : 3;
            sls_r[reg] = logf((float)(cy*cx) + 64.0f);
        }
    }

    const int NC = nTotal >> 6;
    uint4 stg[8];
#pragma unroll
    for (int j = 0; j < 8; ++j) {
        int ci = j*256 + t;
        stg[j] = *(const uint4*)(W + (size_t)(ci >> 5)*256 + (ci & 31)*8);
    }
#pragma unroll
    for (int j = 0; j < 8; ++j) {
        int ci = j*256 + t;
        *(uint4*)(&Bt[0][(ci >> 5)*264 + (ci & 31)*8]) = stg[j];
    }

    for (int nc = 0; nc < NC; ++nc) {
        const int cur = nc & 1;
        __syncthreads();               // Bt[cur] visible; Bt[cur^1] free
        if (nc + 1 < NC) {
            const unsigned short* wp = W + (size_t)(nc + 1)*64*256;
#pragma unroll
            for (int j = 0; j < 8; ++j) {
                int ci = j*256 + t;
                stg[j] = *(const uint4*)(wp + (size_t)(ci >> 5)*256 + (ci & 31)*8);
            }
        }
        f32x4 acc[4];
#pragma unroll
        for (int ct = 0; ct < 4; ++ct) acc[ct] = (f32x4){0.f, 0.f, 0.f, 0.f};
#pragma unroll
        for (int kk = 0; kk < 8; ++kk) {
#pragma unroll
            for (int ct = 0; ct < 4; ++ct) {
                short8 bf = *(const short8*)(&Bt[cur][(ct*16 + col16)*264 + kk*32 + quad*8]);
                acc[ct] = __builtin_amdgcn_mfma_f32_16x16x32_bf16(afr[kk], bf, acc[ct], 0, 0, 0);
            }
        }
        if (nc + 1 < NC) {             // write prefetched chunk (safe: read at nc-1)
#pragma unroll
            for (int j = 0; j < 8; ++j) {
                int ci = j*256 + t;
                *(uint4*)(&Bt[cur ^ 1][(ci >> 5)*264 + (ci & 31)*8]) = stg[j];
            }
        }

        // ---- epilogue for cols [nc*64, nc*64+64) ----
        const int n0 = nc << 6;
        const float* Bp; int noff;
        if (n0 < r1)      { Bp = B0; noff = 0;  }
        else if (n0 < r2) { Bp = B1; noff = r1; }
        else              { Bp = B2; noff = r2; }
        float bias_c[4];
#pragma unroll
        for (int c = 0; c < 4; ++c)
            bias_c[c] = Bp[n0 + c*16 + col16 - noff];

        if (mode == 0) {
            const int region = n0 >> 8;
            float qe_c[4], spt_c[4];
            if (region == 0) {
#pragma unroll
                for (int c = 0; c < 4; ++c) {
                    int col = n0 + c*16 + col16;
                    spt_c[c] = log1pf(expf(temp[(col >> 5) & 7]));
                    qe_c[c]  = qe[col];
                }
            }
#pragma unroll
            for (int reg = 0; reg < 4; ++reg) {
                const int row = m0 + w*16 + quad*4 + reg;
                float v[4];
#pragma unroll
                for (int c = 0; c < 4; ++c) v[c] = acc[c][reg] + bias_c[c];
                if (region <= 1) {
#pragma unroll
                    for (int hp = 0; hp < 2; ++hp) {
                        float s = v[2*hp]*v[2*hp] + v[2*hp+1]*v[2*hp+1];
                        s += __shfl_xor(s, 1); s += __shfl_xor(s, 2);
                        s += __shfl_xor(s, 4); s += __shfl_xor(s, 8);
                        float inv = 1.0f / fmaxf(sqrtf(s), EPSF);
                        v[2*hp]   *= inv;
                        v[2*hp+1] *= inv;
                    }
                }
                if (region == 0) {
#pragma unroll
                    for (int c = 0; c < 4; ++c)
                        v[c] = (v[c] + qe_c[c]) * (spt_c[c] * sls_r[reg]);
                }
                if (region == 3) {
#pragma unroll
                    for (int c = 0; c < 4; ++c) {
                        float g = 0.5f * v[c] * (1.0f + erff(v[c] * 0.70710678118654752f));
                        C[(size_t)row * ldc + n0 + c*16 + col16] = g;
                    }
                } else {
#pragma unroll
                    for (int c = 0; c < 4; ++c)
                        qkv[(size_t)row * 2048 + n0 + c*16 + col16] = f2bf(v[c]);
                }
            }
        } else {
#pragma unroll
            for (int reg = 0; reg < 4; ++reg) {
                const int row = m0 + w*16 + quad*4 + reg;
#pragma unroll
                for (int c = 0; c < 4; ++c)
                    C[(size_t)row * ldc + n0 + c*16 + col16] = acc[c][reg] + bias_c[c];
            }
        }
    }
}

// ---------------------------------------------------------------------------
// fused 8x8 avg-pool + LayerNorm + pooled kv + k-norm -> bf16 pools.
// kv GEMM reads kv_wT[k][o]: lanes consecutive in o -> coalesced.
// ---------------------------------------------------------------------------
__global__ __launch_bounds__(256) void poolkv_kernel(
    const float* __restrict__ buf,
    const float* __restrict__ g, const float* __restrict__ bb,
    const float* __restrict__ kv_wT, const float* __restrict__ kv_b,
    unsigned short* __restrict__ kpb, unsigned short* __restrict__ vpb)
{
    __shared__ float r1[256], r2[256];
    __shared__ float xs[256];
    __shared__ float rowv[512];
    __shared__ float inv[8];
    const int blk = blockIdx.x;          // b*64+p
    const int b = blk >> 6, p = blk & 63;
    const int py = p >> 3, px = p & 7;
    const int t = threadIdx.x;
    float acc = 0.f;
    for (int dy = 0; dy < 8; ++dy)
#pragma unroll
        for (int dx = 0; dx < 8; ++dx) {
            int s = ((py*8+dy) << 6) + px*8 + dx;
            acc += buf[(((size_t)(b*4096+s)) << 10) + 768 + t];
        }
    acc *= (1.0f/64.0f);
    r1[t] = acc; r2[t] = acc*acc;
    __syncthreads();
    for (int off = 128; off; off >>= 1) {
        if (t < off) { r1[t] += r1[t+off]; r2[t] += r2[t+off]; }
        __syncthreads();
    }
    float mu  = r1[0] * (1.0f/256.0f);
    float var = r2[0] * (1.0f/256.0f) - mu*mu;
    float rstd = rsqrtf(var + 1e-5f);
    xs[t] = (acc - mu) * rstd * g[t] + bb[t];
    __syncthreads();
    {
        float s0 = kv_b[t], s1 = kv_b[256 + t];
#pragma unroll 4
        for (int k = 0; k < 256; ++k) {
            float xv = xs[k];
            const float* wr = kv_wT + (size_t)k*512;
            s0 += xv * wr[t];
            s1 += xv * wr[256 + t];
        }
        rowv[t] = s0; rowv[256 + t] = s1;
    }
    __syncthreads();
    if (t < 8) {
        float s = 0.f;
        for (int dd = 0; dd < 32; ++dd) { float v = rowv[t*32+dd]; s += v*v; }
        inv[t] = 1.0f / fmaxf(sqrtf(s), EPSF);
    }
    __syncthreads();
    const int h = t >> 5;
    size_t o = ((((size_t)(b*8+h))*64 + p) << 5) + (t & 31);
    kpb[o] = f2bf(rowv[t] * inv[h]);
    vpb[o] = f2bf(rowv[256 + t]);
}

// ---------------------------------------------------------------------------
// MFMA attention v5 (round-9 structure, unchanged).
// ---------------------------------------------------------------------------
__global__ __launch_bounds__(256, 4) void attn_mfma(
    const unsigned short* __restrict__ qkv,
    unsigned short* __restrict__ ao,
    const unsigned short* __restrict__ kpb,
    const unsigned short* __restrict__ vpb,
    const float* __restrict__ cpb,
    const int*   __restrict__ rpi,
    const float* __restrict__ temp,
    const float* __restrict__ qe,
    const float* __restrict__ rpb,
    const float* __restrict__ lt,
    const float* __restrict__ lb,
    const float* __restrict__ gate)
{
    __shared__ __attribute__((aligned(16))) unsigned short U0[112*40];
    __shared__ __attribute__((aligned(16))) unsigned short U1[64*40];
    __shared__ __attribute__((aligned(16))) unsigned short QS[64*40];
    __shared__ __attribute__((aligned(16))) unsigned short P[64*136];
    __shared__ __attribute__((aligned(16))) unsigned short LTT[16*40];
    __shared__ float invscL[64], gateL[64], rpbL[9], dqvL[16];
    __shared__ int hofs[112];

    const int tile = blockIdx.x;
    const int h    = blockIdx.y;
    const int b    = blockIdx.z;
    const int ty0  = (tile >> 3) << 3;
    const int tx0  = (tile & 7) << 3;
    const int t    = threadIdx.x;

    const float spt = log1pf(expf(temp[h]));
    if (t < 64) {
        int y = ty0 + (t >> 3), x = tx0 + (t & 7);
        int cy = (y == 0 || y == 63) ? 2 : 3;
        int cx = (x == 0 || x == 63) ? 2 : 3;
        invscL[t] = 1.0f / (spt * logf((float)(cy*cx) + 64.0f));
        gateL[t] = gate[(((size_t)(b*4096 + ((y<<6)|x))) << 3) + h];
    } else if (t < 80) {
        int j = t - 64;
        float s = 0.f;
        if (j < 9) {
            s = lb[h*9 + j];
            for (int dd = 0; dd < 32; ++dd)
                s -= qe[h*32+dd] * lt[(h*32+dd)*9 + j];
        }
        dqvL[j] = s;
    } else if (t < 89) {
        rpbL[t-80] = rpb[h*9 + (t-80)];
    } else if (t >= 128 && t < 240) {
        int r = t - 128;
        int off = -1;
        if (r < 100) {
            int y = ty0 + r/10 - 1, x = tx0 + r%10 - 1;
            if (y >= 0 && y < 64 && x >= 0 && x < 64)
                off = (b*4096 + ((y<<6)|x))*2048 + h*32;
        }
        hofs[r] = off;
    }
    for (int i = t; i < 16*32; i += 256) {
        int j = i >> 5, dd = i & 31;
        LTT[j*40 + dd] = (j < 9) ? f2bf(lt[(h*32+dd)*9 + j]) : (unsigned short)0;
    }
    __syncthreads();

    unsigned short* KH = U0;
    unsigned short* KP = U1;
    for (int i = t; i < 112*8; i += 256) {
        int r = i >> 3, sg = i & 7;
        int off = hofs[r];
        uint2 val = {0u, 0u};
        if (off >= 0)
            val = *(const uint2*)(qkv + (size_t)off + 256 + sg*4);
        *(uint2*)(KH + r*40 + sg*4) = val;
    }
    {
        const unsigned short* src = kpb + (size_t)(b*8+h)*2048;
        for (int i = t; i < 512; i += 256)
            *(uint2*)(KP + (i >> 3)*40 + (i & 7)*4) = *(const uint2*)(src + i*4);
    }
    for (int i = t; i < 512; i += 256) {
        int n = i >> 3, sg = i & 7;
        int off = hofs[(n >> 3)*10 + (n & 7) + 11];
        *(uint2*)(QS + n*40 + sg*4) = *(const uint2*)(qkv + (size_t)off + sg*4);
    }
    __syncthreads();

    const int lane  = t & 63;
    const int w     = t >> 6;
    const int col16 = lane & 15;
    const int quad  = lane >> 4;
    const int s_w   = (20*w) & ~15;

    float pbias[4][4];
#pragma unroll
    for (int ct = 0; ct < 4; ++ct) {
        int p = ct*16 + col16;
#pragma unroll
        for (int reg = 0; reg < 4; ++reg) {
            int n = w*16 + quad*4 + reg;
            int y = ty0 + (n >> 3), x = tx0 + (n & 7);
            int ngl = (y << 6) | x;
            pbias[ct][reg] = cpb[((size_t)rpi[(size_t)ngl*64 + p] << 3) + h];
        }
    }

    short8 aq = *(const short8*)(QS + (w*16 + col16)*40 + quad*8);
    f32x4 cl[4], cp[4];
    {
        const f32x4 z = {0.f, 0.f, 0.f, 0.f};
#pragma unroll
        for (int ct = 0; ct < 4; ++ct) {
            short8 bk = *(const short8*)(KH + (s_w + ct*16 + col16)*40 + quad*8);
            cl[ct] = __builtin_amdgcn_mfma_f32_16x16x32_bf16(aq, bk, z, 0, 0, 0);
        }
#pragma unroll
        for (int ct = 0; ct < 4; ++ct) {
            short8 bp = *(const short8*)(KP + (ct*16 + col16)*40 + quad*8);
            cp[ct] = __builtin_amdgcn_mfma_f32_16x16x32_bf16(aq, bp, z, 0, 0, 0);
        }
    }
#pragma unroll
    for (int ct = 0; ct < 4; ++ct) {
        int hk = s_w + ct*16 + col16;
        int ky = hk / 10, kx = hk - ky*10;
#pragma unroll
        for (int reg = 0; reg < 4; ++reg) {
            int n = w*16 + quad*4 + reg;
            int dy = ky - (n >> 3), dx = kx - (n & 7);
            bool valid = (dy >= 0 && dy <= 2 && dx >= 0 && dx <= 2);
            cl[ct][reg] = valid ? (cl[ct][reg] + rpbL[dy*3 + dx]) : -1e30f;
        }
    }
#pragma unroll
    for (int ct = 0; ct < 4; ++ct)
#pragma unroll
        for (int reg = 0; reg < 4; ++reg)
            cp[ct][reg] += pbias[ct][reg];
    float inv[4];
#pragma unroll
    for (int reg = 0; reg < 4; ++reg) {
        float m = -1e30f;
#pragma unroll
        for (int ct = 0; ct < 4; ++ct) m = fmaxf(m, cl[ct][reg]);
#pragma unroll
        for (int ct = 0; ct < 4; ++ct) m = fmaxf(m, cp[ct][reg]);
        m = fmaxf(m, __shfl_xor(m, 1)); m = fmaxf(m, __shfl_xor(m, 2));
        m = fmaxf(m, __shfl_xor(m, 4)); m = fmaxf(m, __shfl_xor(m, 8));
        float s = 0.f;
#pragma unroll
        for (int ct = 0; ct < 4; ++ct) {
            float e = __builtin_expf(cl[ct][reg] - m); cl[ct][reg] = e; s += e;
        }
#pragma unroll
        for (int ct = 0; ct < 4; ++ct) {
            float e = __builtin_expf(cp[ct][reg] - m); cp[ct][reg] = e; s += e;
        }
        s += __shfl_xor(s, 1); s += __shfl_xor(s, 2);
        s += __shfl_xor(s, 4); s += __shfl_xor(s, 8);
        inv[reg] = 1.0f / s;
    }
#pragma unroll
    for (int ct = 0; ct < 4; ++ct)
#pragma unroll
        for (int reg = 0; reg < 4; ++reg) {
            int n = w*16 + quad*4 + reg;
            P[n*136 + ct*16 + col16] = f2bf(cl[ct][reg] * inv[reg]);
        }
#pragma unroll
    for (int ct = 0; ct < 4; ++ct)
#pragma unroll
        for (int reg = 0; reg < 4; ++reg) {
            int n = w*16 + quad*4 + reg;
            P[n*136 + 64 + ct*16 + col16] = f2bf(cp[ct][reg] * inv[reg]);
        }
    {
        const f32x4 z = {0.f, 0.f, 0.f, 0.f};
        short8 blt = *(const short8*)(LTT + col16*40 + quad*8);
        f32x4 cd = __builtin_amdgcn_mfma_f32_16x16x32_bf16(aq, blt, z, 0, 0, 0);
        if (col16 < 9) {
            int dy = col16 / 3, dx = col16 - dy*3;
#pragma unroll
            for (int reg = 0; reg < 4; ++reg) {
                int n = w*16 + quad*4 + reg;
                float ltv = cd[reg] * invscL[n] + dqvL[col16];
                int hk = ((n >> 3) + dy)*10 + (n & 7) + dx;
                int pc = hk - s_w;
                P[n*136 + pc] = f2bf(bf2f(P[n*136 + pc]) + ltv);
            }
        }
    }
    __syncthreads();

    unsigned short* VT  = U0;   // [32][136]
    unsigned short* VPT = U1;   // [32][72]
    for (int i = t; i < 1792; i += 256) {
        int rlo = i & 15, rest = i >> 4;
        int dp = rest & 15, r = (rest >> 4)*16 + rlo;
        int off = hofs[r];
        unsigned val = 0;
        if (off >= 0)
            val = *(const unsigned*)(qkv + (size_t)off + 512 + dp*2);
        VT[(2*dp)*136 + r]   = (unsigned short)(val & 0xffffu);
        VT[(2*dp+1)*136 + r] = (unsigned short)(val >> 16);
    }
    for (int i = t; i < 1024; i += 256) {
        int plo = i & 15, rest = i >> 4;
        int dp = rest & 15, p = (rest >> 4)*16 + plo;
        unsigned val = *(const unsigned*)(vpb + (size_t)(b*8+h)*2048 + p*32 + dp*2);
        VPT[(2*dp)*72 + p]   = (unsigned short)(val & 0xffffu);
        VPT[(2*dp+1)*72 + p] = (unsigned short)(val >> 16);
    }
    __syncthreads();

    f32x4 o0 = {0.f,0.f,0.f,0.f}, o1 = {0.f,0.f,0.f,0.f};
#pragma unroll
    for (int ks = 0; ks < 4; ++ks) {
        short8 a = *(const short8*)(P + (w*16 + col16)*136 + ks*32 + quad*8);
        short8 b0, b1;
        if (ks < 2) {
            b0 = *(const short8*)(VT + col16*136      + s_w + ks*32 + quad*8);
            b1 = *(const short8*)(VT + (16+col16)*136 + s_w + ks*32 + quad*8);
        } else {
            b0 = *(const short8*)(VPT + col16*72      + (ks-2)*32 + quad*8);
            b1 = *(const short8*)(VPT + (16+col16)*72 + (ks-2)*32 + quad*8);
        }
        o0 = __builtin_amdgcn_mfma_f32_16x16x32_bf16(a, b0, o0, 0, 0, 0);
        o1 = __builtin_amdgcn_mfma_f32_16x16x32_bf16(a, b1, o1, 0, 0, 0);
    }
#pragma unroll
    for (int reg = 0; reg < 4; ++reg) {
        int n = w*16 + quad*4 + reg;
        int y = ty0 + (n >> 3), x = tx0 + (n & 7);
        size_t rowo = (size_t)(b*4096 + ((y<<6)|x))*256 + h*32;
        float g = gateL[n];
        ao[rowo + col16]      = f2bf(o0[reg] * g);
        ao[rowo + 16 + col16] = f2bf(o1[reg] * g);
    }
}

// ---------------------------------------------------------------------------
extern "C" void kernel_launch(void* const* d_in, const int* in_sizes, int n_in,
                              void* d_out, int out_size, void* d_ws, size_t ws_size,
                              hipStream_t stream)
{
    const float* x    = (const float*)d_in[0];
    const float* tbl  = (const float*)d_in[1];
    const float* q_w  = (const float*)d_in[2];
    const float* q_b  = (const float*)d_in[3];
    const float* kv_w = (const float*)d_in[4];
    const float* kv_b = (const float*)d_in[5];
    const float* temp = (const float*)d_in[6];
    const float* qe   = (const float*)d_in[7];
    const float* rpb  = (const float*)d_in[8];
    const float* lt   = (const float*)d_in[9];
    const float* lb   = (const float*)d_in[10];
    const float* c1w  = (const float*)d_in[11];
    const float* c1b  = (const float*)d_in[12];
    const float* c2w  = (const float*)d_in[13];
    const float* c2b  = (const float*)d_in[14];
    const float* sr_w = (const float*)d_in[15];
    const float* sr_b = (const float*)d_in[16];
    const float* ng   = (const float*)d_in[17];
    const float* nbias= (const float*)d_in[18];
    const float* wg   = (const float*)d_in[19];
    const float* wg0  = (const float*)d_in[20];
    const float* wg1  = (const float*)d_in[21];
    const float* pw   = (const float*)d_in[22];
    const float* pb   = (const float*)d_in[23];
    const int*   rpi  = (const int*)d_in[24];
    (void)in_sizes; (void)n_in; (void)out_size; (void)ws_size;

    float* buf   = (float*)d_ws;                       // 16384x1024 f32 layout
    unsigned short* qkvb = (unsigned short*)d_ws;      // (16384, 2048) ushort view
    float* xp    = buf + (size_t)16384*1024;           // (unused slot kept)
    float* kpoolf= xp + 65536;
    unsigned short* kpb = (unsigned short*)kpoolf;
    unsigned short* vpb = kpb + 131072;
    float* cpbb  = kpoolf + 131072;
    float* gateb = cpbb + 32768;
    float* kvwT  = gateb + 131072;                     // 131072 f32 (512 KB)
    unsigned short* xbf  = (unsigned short*)(kvwT + 131072);
    unsigned short* ao   = xbf;                        // reuses x_bf (dead after gemm1)
    unsigned short* wcat = xbf + (size_t)16384*256;
    unsigned short* pwbf = wcat + 262144;
    float* out   = (float*)d_out;

    // 1) prep: x->bf16 + gates | weights->bf16 | kv_w transpose | cpb table
    prep_kernel<<<8640,256,0,stream>>>(x, wg, wg0, wg1, q_w, kv_w, sr_w, pw,
                                       tbl, c1w, c1b, c2w, c2b,
                                       xbf, gateb, wcat, pwbf, kvwT, cpbb);
    // 2) fused MFMA GEMM (persistent n-loop, 1 block/CU)
    gemm_nloop<<<256,256,0,stream>>>(xbf, wcat, q_b, kv_b, sr_b,
                                     256, 768, 1024, 0, buf, 1024,
                                     qkvb, temp, qe);
    // 3) pool + LN + pooled kv (coalesced kv_wT reads, bf16 out)
    poolkv_kernel<<<256,256,0,stream>>>(buf, ng, nbias, kvwT, kv_b, kpb, vpb);
    // 4) MFMA attention -> bf16 compact
    attn_mfma<<<dim3(64,8,4),256,0,stream>>>(qkvb, ao, kpb, vpb, cpbb, rpi,
                                             temp, qe, rpb, lt, lb, gateb);
    // 5) output projection (persistent n-loop)
    gemm_nloop<<<256,256,0,stream>>>(ao, pwbf, pb, pb, pb,
                                     1<<30, 1<<30, 256, 1, out, 256,
                                     (unsigned short*)nullptr, nullptr, nullptr);
}

// Round 11
// 249.515 us; speedup vs baseline: 1.1822x; 1.1822x over previous
//
#include <hip/hip_runtime.h>
#include <math.h>

#define EPSF 1.1920929e-07f

typedef __attribute__((ext_vector_type(8))) short short8;
typedef __attribute__((ext_vector_type(4))) float f32x4;

// float -> bf16 (RNE)
static __device__ __forceinline__ unsigned short f2bf(float f) {
    unsigned int u = __float_as_uint(f);
    return (unsigned short)((u + 0x7FFFu + ((u >> 16) & 1u)) >> 16);
}
static __device__ __forceinline__ float bf2f(unsigned short u) {
    return __uint_as_float((unsigned int)u << 16);
}

// ---------------------------------------------------------------------------
// prep: four block-uniform roles.
//  blk <  4096 : x->bf16 (4 rows/block) + fused MoE gate (exact fp32)
//  blk <  4416 : weights->bf16 (wcat q|kv|sr, then pw)
//  blk <  4544 : kv_w transpose -> kv_wT[k][o] f32 (coalesced poolkv reads)
//  else        : CPB table MLP row (4096 rows)
// ---------------------------------------------------------------------------
__global__ __launch_bounds__(256) void prep_kernel(
    const float* __restrict__ x,
    const float* __restrict__ wg,  const float* __restrict__ wg0,
    const float* __restrict__ wg1,
    const float* __restrict__ q_w, const float* __restrict__ kv_w,
    const float* __restrict__ sr_w, const float* __restrict__ pw,
    const float* __restrict__ tbl,
    const float* __restrict__ c1w, const float* __restrict__ c1b,
    const float* __restrict__ c2w, const float* __restrict__ c2b,
    unsigned short* __restrict__ xbf, float* __restrict__ gate,
    unsigned short* __restrict__ wcat, unsigned short* __restrict__ pwbf,
    float* __restrict__ kv_wT, float* __restrict__ cpb)
{
    __shared__ float shpad[512];
    const int blk = blockIdx.x;
    const int t   = threadIdx.x;
    if (blk < 4096) {
        const int j = t & 63;                 // lane within wave; wave = row
        const int row = (blk << 2) + (t >> 6);
        float4 v = *(const float4*)(x + (size_t)row*256 + j*4);
        ushort4 o;
        o.x = f2bf(v.x); o.y = f2bf(v.y); o.z = f2bf(v.z); o.w = f2bf(v.w);
        *(ushort4*)(xbf + (size_t)row*256 + j*4) = o;
        float d[10];
#pragma unroll
        for (int f = 0; f < 10; ++f) {
            const float* wf = (f < 4) ? (wg + f*256) : (f < 6) ? (wg0 + (f-4)*256)
                                                               : (wg1 + (f-6)*256);
            float4 wv = *(const float4*)(wf + j*4);
            float s = v.x*wv.x + v.y*wv.y + v.z*wv.z + v.w*wv.w;
            s += __shfl_xor(s, 32); s += __shfl_xor(s, 16); s += __shfl_xor(s, 8);
            s += __shfl_xor(s, 4);  s += __shfl_xor(s, 2);  s += __shfl_xor(s, 1);
            d[f] = s;
        }
        if (j == 0) {
            float e[4];
            float m = fmaxf(fmaxf(d[0],d[1]), fmaxf(d[2],d[3]));
            float ssum = 0.f;
            for (int i = 0; i < 4; ++i) { e[i] = expf(d[i]-m); ssum += e[i]; }
            for (int i = 0; i < 4; ++i) e[i] /= ssum;
            int i1 = 0;
            for (int i = 1; i < 4; ++i) if (e[i] > e[i1]) i1 = i;
            int i2 = -1;
            for (int i = 0; i < 4; ++i) if (i != i1 && (i2 < 0 || e[i] > e[i2])) i2 = i;
            float rs = fmaxf(e[i1] + e[i2], EPSF);
            float rg[4] = {0.f,0.f,0.f,0.f};
            rg[i1] = e[i1] / rs * 2.f;
            rg[i2] = e[i2] / rs * 2.f;
            float sh[4];
            float m1 = fmaxf(fmaxf(d[6],d[7]), fmaxf(d[8],d[9]));
            float s1 = 0.f;
            for (int i = 0; i < 4; ++i) { sh[i] = expf(d[6+i]-m1); s1 += sh[i]; }
            float mm = fmaxf(d[4], d[5]);
            float e0 = expf(d[4]-mm), e1 = expf(d[5]-mm);
            float w00 = e0/(e0+e1)*2.f, w01 = e1/(e0+e1)*2.f;
            float* gr = gate + ((size_t)row << 3);
            for (int i = 0; i < 4; ++i) gr[i]   = w00 * (sh[i]/s1*4.f);
            for (int i = 0; i < 4; ++i) gr[4+i] = w01 * rg[i];
        }
    } else if (blk < 4416) {
        const int e = ((blk - 4096)*256 + t)*4;
        if (e < 262144) {
            int n = e >> 8, k = e & 255;
            const float* src = (n < 256) ? (q_w + n*256) :
                               (n < 768) ? (kv_w + (n-256)*256) : (sr_w + (n-768)*256);
            float4 v = *(const float4*)(src + k);
            ushort4 o;
            o.x = f2bf(v.x); o.y = f2bf(v.y); o.z = f2bf(v.z); o.w = f2bf(v.w);
            *(ushort4*)(wcat + e) = o;
        } else {
            int e2 = e - 262144;
            float4 v = *(const float4*)(pw + e2);
            ushort4 o;
            o.x = f2bf(v.x); o.y = f2bf(v.y); o.z = f2bf(v.z); o.w = f2bf(v.w);
            *(ushort4*)(pwbf + e2) = o;
        }
    } else if (blk < 4544) {
        const int e = ((blk - 4416)*256 + t)*4;     // over 131072 kv_w elems
        int o = e >> 8, k = e & 255;
        float4 v = *(const float4*)(kv_w + e);
        kv_wT[(k+0)*512 + o] = v.x;
        kv_wT[(k+1)*512 + o] = v.y;
        kv_wT[(k+2)*512 + o] = v.z;
        kv_wT[(k+3)*512 + o] = v.w;
    } else {
        const int r = blk - 4544;
        const float c0 = tbl[(size_t)r*2], c1 = tbl[(size_t)r*2+1];
        for (int i = t; i < 512; i += 256)
            shpad[i] = fmaxf(c0*c1w[i*2] + c1*c1w[i*2+1] + c1b[i], 0.f);
        __syncthreads();
        const int hh = t >> 5, dd = t & 31;
        float s = 0.f;
        for (int i = dd; i < 512; i += 32) s += shpad[i] * c2w[hh*512+i];
        for (int off = 16; off; off >>= 1) s += __shfl_xor(s, off, 32);
        if (dd == 0) cpb[((size_t)r << 3) + hh] = s + c2b[hh];
    }
}

// ---------------------------------------------------------------------------
// MFMA bf16 GEMM, K=256, 64x64 tile, A-strip in registers (no A LDS, no
// barrier for A), B staged once in 33 KB LDS -> 4 blocks/CU (round-10 lesson:
// many blocks > persistent; round-9 lesson: single K-pass > k-loop drains).
// mode 0: fused q|k|v|sr producer. mode 1: bias-add f32 GEMM.
// ---------------------------------------------------------------------------
__global__ __launch_bounds__(256) void gemm_mfma(
    const unsigned short* __restrict__ A,
    const unsigned short* __restrict__ W,
    const float* __restrict__ B0, const float* __restrict__ B1,
    const float* __restrict__ B2,
    int r1, int r2, int mode,
    float* __restrict__ C, int ldc,
    unsigned short* __restrict__ qkv,
    const float* __restrict__ temp, const float* __restrict__ qe)
{
    __shared__ __attribute__((aligned(16))) unsigned short Bt[64*264];
    const int m0 = blockIdx.y << 6;
    const int n0 = blockIdx.x << 6;
    const int t  = threadIdx.x;
    const int w  = t >> 6;
    const int col16 = t & 15;
    const int quad  = (t & 63) >> 4;

    const float* Bp; int noff;
    if (n0 < r1)      { Bp = B0; noff = 0;  }
    else if (n0 < r2) { Bp = B1; noff = r1; }
    else              { Bp = B2; noff = r2; }

    // ---- A strip -> registers (16 rows per wave, 8 short8 = 32 VGPRs) ----
    short8 afr[8];
    {
        const unsigned short* ap = A + (size_t)(m0 + w*16 + col16)*256 + quad*8;
#pragma unroll
        for (int kk = 0; kk < 8; ++kk)
            afr[kk] = *(const short8*)(ap + kk*32);
    }
    // ---- stage B tile once (8 uint4 per thread), one barrier ----
#pragma unroll
    for (int j = 0; j < 8; ++j) {
        int ci = j*256 + t;            // 16B chunk: row = ci>>5, chunk = ci&31
        int r = ci >> 5, c = ci & 31;
        uint4 bv = *(const uint4*)(W + (size_t)(n0 + r)*256 + c*8);
        *(uint4*)(Bt + r*264 + c*8) = bv;
    }
    __syncthreads();

    f32x4 acc[4];
#pragma unroll
    for (int ct = 0; ct < 4; ++ct) acc[ct] = (f32x4){0.f, 0.f, 0.f, 0.f};
#pragma unroll
    for (int kk = 0; kk < 8; ++kk) {
#pragma unroll
        for (int ct = 0; ct < 4; ++ct) {
            short8 bf = *(const short8*)(Bt + (ct*16 + col16)*264 + kk*32 + quad*8);
            acc[ct] = __builtin_amdgcn_mfma_f32_16x16x32_bf16(afr[kk], bf, acc[ct], 0, 0, 0);
        }
    }

    float bias_c[4];
#pragma unroll
    for (int ct = 0; ct < 4; ++ct)
        bias_c[ct] = Bp[n0 + ct*16 + col16 - noff];

    if (mode == 0) {
        const int region = n0 >> 8;    // 0=q, 1=k, 2=v, 3=sr
        float qe_c[4], spt_c[4];
        if (region == 0) {
#pragma unroll
            for (int c = 0; c < 4; ++c) {
                int col = n0 + c*16 + col16;
                spt_c[c] = log1pf(expf(temp[(col >> 5) & 7]));
                qe_c[c]  = qe[col];
            }
        }
#pragma unroll
        for (int reg = 0; reg < 4; ++reg) {
            const int row = m0 + w*16 + quad*4 + reg;
            float v[4];
#pragma unroll
            for (int c = 0; c < 4; ++c) v[c] = acc[c][reg] + bias_c[c];
            if (region <= 1) {             // q,k: per-head L2 norm
#pragma unroll
                for (int hp = 0; hp < 2; ++hp) {
                    float s = v[2*hp]*v[2*hp] + v[2*hp+1]*v[2*hp+1];
                    s += __shfl_xor(s, 1); s += __shfl_xor(s, 2);
                    s += __shfl_xor(s, 4); s += __shfl_xor(s, 8);
                    float inv = 1.0f / fmaxf(sqrtf(s), EPSF);
                    v[2*hp]   *= inv;
                    v[2*hp+1] *= inv;
                }
            }
            if (region == 0) {             // q: (qn+qe)*softplus(temp)*sls
                int n = row & 4095;
                int y = n >> 6, x = n & 63;
                int cy = (y == 0 || y == 63) ? 2 : 3;
                int cx = (x == 0 || x == 63) ? 2 : 3;
                float sls = logf((float)(cy*cx) + 64.0f);
#pragma unroll
                for (int c = 0; c < 4; ++c)
                    v[c] = (v[c] + qe_c[c]) * (spt_c[c] * sls);
            }
            if (region == 3) {             // sr: gelu -> f32
#pragma unroll
                for (int c = 0; c < 4; ++c) {
                    float g = 0.5f * v[c] * (1.0f + erff(v[c] * 0.70710678118654752f));
                    C[(size_t)row * ldc + n0 + c*16 + col16] = g;
                }
            } else {                       // q/k/v: packed bf16
#pragma unroll
                for (int c = 0; c < 4; ++c)
                    qkv[(size_t)row * 2048 + n0 + c*16 + col16] = f2bf(v[c]);
            }
        }
    } else {
#pragma unroll
        for (int reg = 0; reg < 4; ++reg) {
            const int row = m0 + w*16 + quad*4 + reg;
#pragma unroll
            for (int c = 0; c < 4; ++c)
                C[(size_t)row * ldc + n0 + c*16 + col16] = acc[c][reg] + bias_c[c];
        }
    }
}

// ---------------------------------------------------------------------------
// fused 8x8 avg-pool + LayerNorm + pooled kv + k-norm -> bf16 pools.
// kv GEMM reads kv_wT[k][o]: lanes consecutive in o -> coalesced.
// ---------------------------------------------------------------------------
__global__ __launch_bounds__(256) void poolkv_kernel(
    const float* __restrict__ buf,
    const float* __restrict__ g, const float* __restrict__ bb,
    const float* __restrict__ kv_wT, const float* __restrict__ kv_b,
    unsigned short* __restrict__ kpb, unsigned short* __restrict__ vpb)
{
    __shared__ float r1[256], r2[256];
    __shared__ float xs[256];
    __shared__ float rowv[512];
    __shared__ float inv[8];
    const int blk = blockIdx.x;          // b*64+p
    const int b = blk >> 6, p = blk & 63;
    const int py = p >> 3, px = p & 7;
    const int t = threadIdx.x;
    float acc = 0.f;
    for (int dy = 0; dy < 8; ++dy)
#pragma unroll
        for (int dx = 0; dx < 8; ++dx) {
            int s = ((py*8+dy) << 6) + px*8 + dx;
            acc += buf[(((size_t)(b*4096+s)) << 10) + 768 + t];
        }
    acc *= (1.0f/64.0f);
    r1[t] = acc; r2[t] = acc*acc;
    __syncthreads();
    for (int off = 128; off; off >>= 1) {
        if (t < off) { r1[t] += r1[t+off]; r2[t] += r2[t+off]; }
        __syncthreads();
    }
    float mu  = r1[0] * (1.0f/256.0f);
    float var = r2[0] * (1.0f/256.0f) - mu*mu;
    float rstd = rsqrtf(var + 1e-5f);
    xs[t] = (acc - mu) * rstd * g[t] + bb[t];
    __syncthreads();
    {
        float s0 = kv_b[t], s1 = kv_b[256 + t];
#pragma unroll 4
        for (int k = 0; k < 256; ++k) {
            float xv = xs[k];
            const float* wr = kv_wT + (size_t)k*512;
            s0 += xv * wr[t];
            s1 += xv * wr[256 + t];
        }
        rowv[t] = s0; rowv[256 + t] = s1;
    }
    __syncthreads();
    if (t < 8) {
        float s = 0.f;
        for (int dd = 0; dd < 32; ++dd) { float v = rowv[t*32+dd]; s += v*v; }
        inv[t] = 1.0f / fmaxf(sqrtf(s), EPSF);
    }
    __syncthreads();
    const int h = t >> 5;
    size_t o = ((((size_t)(b*8+h))*64 + p) << 5) + (t & 31);
    kpb[o] = f2bf(rowv[t] * inv[h]);
    vpb[o] = f2bf(rowv[256 + t]);
}

// ---------------------------------------------------------------------------
// MFMA attention v5 (round-9 structure, unchanged).
// ---------------------------------------------------------------------------
__global__ __launch_bounds__(256, 4) void attn_mfma(
    const unsigned short* __restrict__ qkv,
    unsigned short* __restrict__ ao,
    const unsigned short* __restrict__ kpb,
    const unsigned short* __restrict__ vpb,
    const float* __restrict__ cpb,
    const int*   __restrict__ rpi,
    const float* __restrict__ temp,
    const float* __restrict__ qe,
    const float* __restrict__ rpb,
    const float* __restrict__ lt,
    const float* __restrict__ lb,
    const float* __restrict__ gate)
{
    __shared__ __attribute__((aligned(16))) unsigned short U0[112*40];
    __shared__ __attribute__((aligned(16))) unsigned short U1[64*40];
    __shared__ __attribute__((aligned(16))) unsigned short QS[64*40];
    __shared__ __attribute__((aligned(16))) unsigned short P[64*136];
    __shared__ __attribute__((aligned(16))) unsigned short LTT[16*40];
    __shared__ float invscL[64], gateL[64], rpbL[9], dqvL[16];
    __shared__ int hofs[112];

    const int tile = blockIdx.x;
    const int h    = blockIdx.y;
    const int b    = blockIdx.z;
    const int ty0  = (tile >> 3) << 3;
    const int tx0  = (tile & 7) << 3;
    const int t    = threadIdx.x;

    const float spt = log1pf(expf(temp[h]));
    if (t < 64) {
        int y = ty0 + (t >> 3), x = tx0 + (t & 7);
        int cy = (y == 0 || y == 63) ? 2 : 3;
        int cx = (x == 0 || x == 63) ? 2 : 3;
        invscL[t] = 1.0f / (spt * logf((float)(cy*cx) + 64.0f));
        gateL[t] = gate[(((size_t)(b*4096 + ((y<<6)|x))) << 3) + h];
    } else if (t < 80) {
        int j = t - 64;
        float s = 0.f;
        if (j < 9) {
            s = lb[h*9 + j];
            for (int dd = 0; dd < 32; ++dd)
                s -= qe[h*32+dd] * lt[(h*32+dd)*9 + j];
        }
        dqvL[j] = s;
    } else if (t < 89) {
        rpbL[t-80] = rpb[h*9 + (t-80)];
    } else if (t >= 128 && t < 240) {
        int r = t - 128;
        int off = -1;
        if (r < 100) {
            int y = ty0 + r/10 - 1, x = tx0 + r%10 - 1;
            if (y >= 0 && y < 64 && x >= 0 && x < 64)
                off = (b*4096 + ((y<<6)|x))*2048 + h*32;
        }
        hofs[r] = off;
    }
    for (int i = t; i < 16*32; i += 256) {
        int j = i >> 5, dd = i & 31;
        LTT[j*40 + dd] = (j < 9) ? f2bf(lt[(h*32+dd)*9 + j]) : (unsigned short)0;
    }
    __syncthreads();

    unsigned short* KH = U0;
    unsigned short* KP = U1;
    for (int i = t; i < 112*8; i += 256) {
        int r = i >> 3, sg = i & 7;
        int off = hofs[r];
        uint2 val = {0u, 0u};
        if (off >= 0)
            val = *(const uint2*)(qkv + (size_t)off + 256 + sg*4);
        *(uint2*)(KH + r*40 + sg*4) = val;
    }
    {
        const unsigned short* src = kpb + (size_t)(b*8+h)*2048;
        for (int i = t; i < 512; i += 256)
            *(uint2*)(KP + (i >> 3)*40 + (i & 7)*4) = *(const uint2*)(src + i*4);
    }
    for (int i = t; i < 512; i += 256) {
        int n = i >> 3, sg = i & 7;
        int off = hofs[(n >> 3)*10 + (n & 7) + 11];
        *(uint2*)(QS + n*40 + sg*4) = *(const uint2*)(qkv + (size_t)off + sg*4);
    }
    __syncthreads();

    const int lane  = t & 63;
    const int w     = t >> 6;
    const int col16 = lane & 15;
    const int quad  = lane >> 4;
    const int s_w   = (20*w) & ~15;

    float pbias[4][4];
#pragma unroll
    for (int ct = 0; ct < 4; ++ct) {
        int p = ct*16 + col16;
#pragma unroll
        for (int reg = 0; reg < 4; ++reg) {
            int n = w*16 + quad*4 + reg;
            int y = ty0 + (n >> 3), x = tx0 + (n & 7);
            int ngl = (y << 6) | x;
            pbias[ct][reg] = cpb[((size_t)rpi[(size_t)ngl*64 + p] << 3) + h];
        }
    }

    short8 aq = *(const short8*)(QS + (w*16 + col16)*40 + quad*8);
    f32x4 cl[4], cp[4];
    {
        const f32x4 z = {0.f, 0.f, 0.f, 0.f};
#pragma unroll
        for (int ct = 0; ct < 4; ++ct) {
            short8 bk = *(const short8*)(KH + (s_w + ct*16 + col16)*40 + quad*8);
            cl[ct] = __builtin_amdgcn_mfma_f32_16x16x32_bf16(aq, bk, z, 0, 0, 0);
        }
#pragma unroll
        for (int ct = 0; ct < 4; ++ct) {
            short8 bp = *(const short8*)(KP + (ct*16 + col16)*40 + quad*8);
            cp[ct] = __builtin_amdgcn_mfma_f32_16x16x32_bf16(aq, bp, z, 0, 0, 0);
        }
    }
#pragma unroll
    for (int ct = 0; ct < 4; ++ct) {
        int hk = s_w + ct*16 + col16;
        int ky = hk / 10, kx = hk - ky*10;
#pragma unroll
        for (int reg = 0; reg < 4; ++reg) {
            int n = w*16 + quad*4 + reg;
            int dy = ky - (n >> 3), dx = kx - (n & 7);
            bool valid = (dy >= 0 && dy <= 2 && dx >= 0 && dx <= 2);
            cl[ct][reg] = valid ? (cl[ct][reg] + rpbL[dy*3 + dx]) : -1e30f;
        }
    }
#pragma unroll
    for (int ct = 0; ct < 4; ++ct)
#pragma unroll
        for (int reg = 0; reg < 4; ++reg)
            cp[ct][reg] += pbias[ct][reg];
    float inv[4];
#pragma unroll
    for (int reg = 0; reg < 4; ++reg) {
        float m = -1e30f;
#pragma unroll
        for (int ct = 0; ct < 4; ++ct) m = fmaxf(m, cl[ct][reg]);
#pragma unroll
        for (int ct = 0; ct < 4; ++ct) m = fmaxf(m, cp[ct][reg]);
        m = fmaxf(m, __shfl_xor(m, 1)); m = fmaxf(m, __shfl_xor(m, 2));
        m = fmaxf(m, __shfl_xor(m, 4)); m = fmaxf(m, __shfl_xor(m, 8));
        float s = 0.f;
#pragma unroll
        for (int ct = 0; ct < 4; ++ct) {
            float e = __builtin_expf(cl[ct][reg] - m); cl[ct][reg] = e; s += e;
        }
#pragma unroll
        for (int ct = 0; ct < 4; ++ct) {
            float e = __builtin_expf(cp[ct][reg] - m); cp[ct][reg] = e; s += e;
        }
        s += __shfl_xor(s, 1); s += __shfl_xor(s, 2);
        s += __shfl_xor(s, 4); s += __shfl_xor(s, 8);
        inv[reg] = 1.0f / s;
    }
#pragma unroll
    for (int ct = 0; ct < 4; ++ct)
#pragma unroll
        for (int reg = 0; reg < 4; ++reg) {
            int n = w*16 + quad*4 + reg;
            P[n*136 + ct*16 + col16] = f2bf(cl[ct][reg] * inv[reg]);
        }
#pragma unroll
    for (int ct = 0; ct < 4; ++ct)
#pragma unroll
        for (int reg = 0; reg < 4; ++reg) {
            int n = w*16 + quad*4 + reg;
            P[n*136 + 64 + ct*16 + col16] = f2bf(cp[ct][reg] * inv[reg]);
        }
    {
        const f32x4 z = {0.f, 0.f, 0.f, 0.f};
        short8 blt = *(const short8*)(LTT + col16*40 + quad*8);
        f32x4 cd = __builtin_amdgcn_mfma_f32_16x16x32_bf16(aq, blt, z, 0, 0, 0);
        if (col16 < 9) {
            int dy = col16 / 3, dx = col16 - dy*3;
#pragma unroll
            for (int reg = 0; reg < 4; ++reg) {
                int n = w*16 + quad*4 + reg;
                float ltv = cd[reg] * invscL[n] + dqvL[col16];
                int hk = ((n >> 3) + dy)*10 + (n & 7) + dx;
                int pc = hk - s_w;
                P[n*136 + pc] = f2bf(bf2f(P[n*136 + pc]) + ltv);
            }
        }
    }
    __syncthreads();

    unsigned short* VT  = U0;   // [32][136]
    unsigned short* VPT = U1;   // [32][72]
    for (int i = t; i < 1792; i += 256) {
        int rlo = i & 15, rest = i >> 4;
        int dp = rest & 15, r = (rest >> 4)*16 + rlo;
        int off = hofs[r];
        unsigned val = 0;
        if (off >= 0)
            val = *(const unsigned*)(qkv + (size_t)off + 512 + dp*2);
        VT[(2*dp)*136 + r]   = (unsigned short)(val & 0xffffu);
        VT[(2*dp+1)*136 + r] = (unsigned short)(val >> 16);
    }
    for (int i = t; i < 1024; i += 256) {
        int plo = i & 15, rest = i >> 4;
        int dp = rest & 15, p = (rest >> 4)*16 + plo;
        unsigned val = *(const unsigned*)(vpb + (size_t)(b*8+h)*2048 + p*32 + dp*2);
        VPT[(2*dp)*72 + p]   = (unsigned short)(val & 0xffffu);
        VPT[(2*dp+1)*72 + p] = (unsigned short)(val >> 16);
    }
    __syncthreads();

    f32x4 o0 = {0.f,0.f,0.f,0.f}, o1 = {0.f,0.f,0.f,0.f};
#pragma unroll
    for (int ks = 0; ks < 4; ++ks) {
        short8 a = *(const short8*)(P + (w*16 + col16)*136 + ks*32 + quad*8);
        short8 b0, b1;
        if (ks < 2) {
            b0 = *(const short8*)(VT + col16*136      + s_w + ks*32 + quad*8);
            b1 = *(const short8*)(VT + (16+col16)*136 + s_w + ks*32 + quad*8);
        } else {
            b0 = *(const short8*)(VPT + col16*72      + (ks-2)*32 + quad*8);
            b1 = *(const short8*)(VPT + (16+col16)*72 + (ks-2)*32 + quad*8);
        }
        o0 = __builtin_amdgcn_mfma_f32_16x16x32_bf16(a, b0, o0, 0, 0, 0);
        o1 = __builtin_amdgcn_mfma_f32_16x16x32_bf16(a, b1, o1, 0, 0, 0);
    }
#pragma unroll
    for (int reg = 0; reg < 4; ++reg) {
        int n = w*16 + quad*4 + reg;
        int y = ty0 + (n >> 3), x = tx0 + (n & 7);
        size_t rowo = (size_t)(b*4096 + ((y<<6)|x))*256 + h*32;
        float g = gateL[n];
        ao[rowo + col16]      = f2bf(o0[reg] * g);
        ao[rowo + 16 + col16] = f2bf(o1[reg] * g);
    }
}

// ---------------------------------------------------------------------------
extern "C" void kernel_launch(void* const* d_in, const int* in_sizes, int n_in,
                              void* d_out, int out_size, void* d_ws, size_t ws_size,
                              hipStream_t stream)
{
    const float* x    = (const float*)d_in[0];
    const float* tbl  = (const float*)d_in[1];
    const float* q_w  = (const float*)d_in[2];
    const float* q_b  = (const float*)d_in[3];
    const float* kv_w = (const float*)d_in[4];
    const float* kv_b = (const float*)d_in[5];
    const float* temp = (const float*)d_in[6];
    const float* qe   = (const float*)d_in[7];
    const float* rpb  = (const float*)d_in[8];
    const float* lt   = (const float*)d_in[9];
    const float* lb   = (const float*)d_in[10];
    const float* c1w  = (const float*)d_in[11];
    const float* c1b  = (const float*)d_in[12];
    const float* c2w  = (const float*)d_in[13];
    const float* c2b  = (const float*)d_in[14];
    const float* sr_w = (const float*)d_in[15];
    const float* sr_b = (const float*)d_in[16];
    const float* ng   = (const float*)d_in[17];
    const float* nbias= (const float*)d_in[18];
    const float* wg   = (const float*)d_in[19];
    const float* wg0  = (const float*)d_in[20];
    const float* wg1  = (const float*)d_in[21];
    const float* pw   = (const float*)d_in[22];
    const float* pb   = (const float*)d_in[23];
    const int*   rpi  = (const int*)d_in[24];
    (void)in_sizes; (void)n_in; (void)out_size; (void)ws_size;

    float* buf   = (float*)d_ws;                       // 16384x1024 f32 layout
    unsigned short* qkvb = (unsigned short*)d_ws;      // (16384, 2048) ushort view
    float* xp    = buf + (size_t)16384*1024;
    float* kpoolf= xp + 65536;
    unsigned short* kpb = (unsigned short*)kpoolf;
    unsigned short* vpb = kpb + 131072;
    float* cpbb  = kpoolf + 131072;
    float* gateb = cpbb + 32768;
    float* kvwT  = gateb + 131072;                     // 131072 f32 (512 KB)
    unsigned short* xbf  = (unsigned short*)(kvwT + 131072);
    unsigned short* ao   = xbf;                        // reuses x_bf (dead after gemm1)
    unsigned short* wcat = xbf + (size_t)16384*256;
    unsigned short* pwbf = wcat + 262144;
    float* out   = (float*)d_out;

    // 1) prep: x->bf16 + gates | weights->bf16 | kv_w transpose | cpb table
    prep_kernel<<<8640,256,0,stream>>>(x, wg, wg0, wg1, q_w, kv_w, sr_w, pw,
                                       tbl, c1w, c1b, c2w, c2b,
                                       xbf, gateb, wcat, pwbf, kvwT, cpbb);
    // 2) fused MFMA GEMM (64x64 tiles, A-in-regs, 4 blocks/CU)
    gemm_mfma<<<dim3(16,256),256,0,stream>>>(xbf, wcat, q_b, kv_b, sr_b,
                                             256, 768, 0, buf, 1024,
                                             qkvb, temp, qe);
    // 3) pool + LN + pooled kv (coalesced kv_wT reads, bf16 out)
    poolkv_kernel<<<256,256,0,stream>>>(buf, ng, nbias, kvwT, kv_b, kpb, vpb);
    // 4) MFMA attention -> bf16 compact
    attn_mfma<<<dim3(64,8,4),256,0,stream>>>(qkvb, ao, kpb, vpb, cpbb, rpi,
                                             temp, qe, rpb, lt, lb, gateb);
    // 5) output projection (same GEMM, mode 1)
    gemm_mfma<<<dim3(4,256),256,0,stream>>>(ao, pwbf, pb, pb, pb,
                                            1<<30, 1<<30, 1, out, 256,
                                            (unsigned short*)nullptr, nullptr, nullptr);
}